// Round 5
// baseline (314.871 us; speedup 1.0000x reference)
//
#include <hip/hip_runtime.h>
#include <hip/hip_bf16.h>

#define THREADS 256
#define GTHREADS 512   // gemm block size (8 waves)

// ---------------------------------------------------------------------------
// Dual GEMM: outl = in @ Wl, outr = in @ Wr.   in: [nrows, K], W: [K, 64].
// R rows per wave (lane = output column). W staged in LDS transposed to
// [K/4][64] float4 so each lane reads its 4 k-values with ONE ds_read_b128
// (lane-contiguous 16B = conflict-free). x row loads are per-lane VECTOR
// loads (same addr across lanes = L1 broadcast) -> vmcnt-tracked, in-order,
// so the 1-deep prefetch actually pipelines (SMEM/lgkmcnt path did not).
// ---------------------------------------------------------------------------
template<int K, int R>
__global__ __launch_bounds__(GTHREADS, 4) void gemm_dual(
    const float* __restrict__ in, const float* __restrict__ Wl,
    const float* __restrict__ Wr, float* __restrict__ outl,
    float* __restrict__ outr, int nrows)
{
    constexpr int K4 = K / 4;
    __shared__ float4 sWl[K4 * 64];
    __shared__ float4 sWr[K4 * 64];
    for (int i = threadIdx.x; i < K4 * 64; i += GTHREADS) {
        const int k4 = i >> 6;
        const int c  = i & 63;
        const int kb = k4 * 4;
        sWl[i] = make_float4(Wl[(kb + 0) * 64 + c], Wl[(kb + 1) * 64 + c],
                             Wl[(kb + 2) * 64 + c], Wl[(kb + 3) * 64 + c]);
        sWr[i] = make_float4(Wr[(kb + 0) * 64 + c], Wr[(kb + 1) * 64 + c],
                             Wr[(kb + 2) * 64 + c], Wr[(kb + 3) * 64 + c]);
    }
    __syncthreads();

    const int lane = threadIdx.x & 63;
    const int wid  = threadIdx.x >> 6;            // 0..7
    const int row0 = blockIdx.x * (8 * R) + wid * R;
    if (row0 >= nrows) return;

    // clamp rows for loads (branch-free), guard stores
    int rr[R];
    #pragma unroll
    for (int r = 0; r < R; ++r)
        rr[r] = (row0 + r < nrows) ? (row0 + r) : (nrows - 1);

    float accl[R], accr[R];
    #pragma unroll
    for (int r = 0; r < R; ++r) { accl[r] = 0.f; accr[r] = 0.f; }

    // prologue: prefetch k4 = 0 (vector loads, same addr across lanes)
    float4 xv[R];
    #pragma unroll
    for (int r = 0; r < R; ++r)
        xv[r] = *reinterpret_cast<const float4*>(in + (size_t)rr[r] * K);

    #pragma unroll 2
    for (int k4 = 0; k4 < K4; ++k4) {
        // prefetch next chunk (clamped, branch-free; last iter redundant)
        const int kn = (k4 + 1 < K4) ? (k4 + 1) * 4 : k4 * 4;
        float4 xn[R];
        #pragma unroll
        for (int r = 0; r < R; ++r)
            xn[r] = *reinterpret_cast<const float4*>(in + (size_t)rr[r] * K + kn);

        const float4 wl = sWl[k4 * 64 + lane];    // ds_read_b128
        const float4 wr = sWr[k4 * 64 + lane];    // ds_read_b128
        #pragma unroll
        for (int r = 0; r < R; ++r) {
            accl[r] = fmaf(xv[r].x, wl.x, accl[r]);
            accl[r] = fmaf(xv[r].y, wl.y, accl[r]);
            accl[r] = fmaf(xv[r].z, wl.z, accl[r]);
            accl[r] = fmaf(xv[r].w, wl.w, accl[r]);
            accr[r] = fmaf(xv[r].x, wr.x, accr[r]);
            accr[r] = fmaf(xv[r].y, wr.y, accr[r]);
            accr[r] = fmaf(xv[r].z, wr.z, accr[r]);
            accr[r] = fmaf(xv[r].w, wr.w, accr[r]);
        }
        #pragma unroll
        for (int r = 0; r < R; ++r) xv[r] = xn[r];
    }

    #pragma unroll
    for (int r = 0; r < R; ++r) {
        if (row0 + r < nrows) {
            outl[(size_t)(row0 + r) * 64 + lane] = accl[r];
            outr[(size_t)(row0 + r) * 64 + lane] = accr[r];
        }
    }
}

// ---------------------------------------------------------------------------
// CSR build: histogram of dst, exclusive scan, placement.
// ---------------------------------------------------------------------------
__global__ __launch_bounds__(THREADS) void hist_kernel(
    const int* __restrict__ dst, int* __restrict__ deg, int nedges)
{
    const int e = blockIdx.x * THREADS + threadIdx.x;
    if (e < nedges) atomicAdd(&deg[dst[e]], 1);
}

__global__ __launch_bounds__(THREADS) void scan_reduce(
    const int* __restrict__ deg, int* __restrict__ bsum, int n)
{
    __shared__ int s[THREADS];
    const int i = blockIdx.x * THREADS + threadIdx.x;
    s[threadIdx.x] = (i < n) ? deg[i] : 0;
    __syncthreads();
    for (int off = THREADS / 2; off > 0; off >>= 1) {
        if (threadIdx.x < off) s[threadIdx.x] += s[threadIdx.x + off];
        __syncthreads();
    }
    if (threadIdx.x == 0) bsum[blockIdx.x] = s[0];
}

// single block; nb <= THREADS
__global__ __launch_bounds__(THREADS) void scan_top(int* __restrict__ bsum, int nb)
{
    __shared__ int s[THREADS];
    const int t = threadIdx.x;
    const int v = (t < nb) ? bsum[t] : 0;
    s[t] = v;
    __syncthreads();
    for (int off = 1; off < THREADS; off <<= 1) {
        const int a = (t >= off) ? s[t - off] : 0;
        __syncthreads();
        s[t] += a;
        __syncthreads();
    }
    if (t < nb) bsum[t] = s[t] - v;   // exclusive
}

__global__ __launch_bounds__(THREADS) void scan_apply(
    const int* __restrict__ deg, const int* __restrict__ bsum,
    int* __restrict__ offs, int* __restrict__ cursor, int n)
{
    __shared__ int s[THREADS];
    const int t = threadIdx.x;
    const int i = blockIdx.x * THREADS + t;
    const int v = (i < n) ? deg[i] : 0;
    s[t] = v;
    __syncthreads();
    for (int off = 1; off < THREADS; off <<= 1) {
        const int a = (t >= off) ? s[t - off] : 0;
        __syncthreads();
        s[t] += a;
        __syncthreads();
    }
    if (i < n) {
        const int ex = bsum[blockIdx.x] + s[t] - v;
        offs[i] = ex;
        cursor[i] = ex;
    }
}

__global__ __launch_bounds__(THREADS) void place_kernel(
    const int* __restrict__ src, const int* __restrict__ dst,
    int* __restrict__ cursor, int* __restrict__ csr, int nedges)
{
    const int e = blockIdx.x * THREADS + threadIdx.x;
    if (e < nedges) {
        const int pos = atomicAdd(&cursor[dst[e]], 1);
        csr[pos] = src[e];
    }
}

// ---------------------------------------------------------------------------
// Fused mean-aggregate + combine:
//   out[node,lane] = [relu]( (sum_{s in csr[node]} y[s,lane]) / max(deg,1)
//                            + bias[lane] + right[node,lane] )
// One wave per node, lane = channel. Edge rows are coalesced 256B gathers.
// ---------------------------------------------------------------------------
__global__ __launch_bounds__(THREADS) void aggregate_fused(
    const float* __restrict__ y, const int* __restrict__ csr,
    const int* __restrict__ offs, const int* __restrict__ deg,
    const float* __restrict__ right, const float* __restrict__ bias,
    float* __restrict__ out, int n, int relu)
{
    int node = blockIdx.x * (THREADS / 64) + (threadIdx.x >> 6);
    if (node >= n) return;
    node = __builtin_amdgcn_readfirstlane(node);   // wave-uniform
    const int lane = threadIdx.x & 63;
    const int start = __builtin_amdgcn_readfirstlane(offs[node]);
    const int d     = __builtin_amdgcn_readfirstlane(deg[node]);

    float acc = 0.f;
    int i = 0;
    for (; i + 4 <= d; i += 4) {
        const int s0 = __builtin_amdgcn_readfirstlane(csr[start + i + 0]);
        const int s1 = __builtin_amdgcn_readfirstlane(csr[start + i + 1]);
        const int s2 = __builtin_amdgcn_readfirstlane(csr[start + i + 2]);
        const int s3 = __builtin_amdgcn_readfirstlane(csr[start + i + 3]);
        const float a0 = y[(size_t)s0 * 64 + lane];
        const float a1 = y[(size_t)s1 * 64 + lane];
        const float a2 = y[(size_t)s2 * 64 + lane];
        const float a3 = y[(size_t)s3 * 64 + lane];
        acc += a0 + a1 + a2 + a3;
    }
    for (; i < d; ++i) {
        const int s = __builtin_amdgcn_readfirstlane(csr[start + i]);
        acc += y[(size_t)s * 64 + lane];
    }

    const float inv = 1.0f / (float)(d > 0 ? d : 1);
    float v = fmaf(acc, inv, bias[lane] + right[(size_t)node * 64 + lane]);
    if (relu) v = fmaxf(v, 0.f);
    out[(size_t)node * 64 + lane] = v;
}

// ---------------------------------------------------------------------------
// out[e] = dot(z[src[e]], z[dst[e]])  over 64 ch; 16 lanes/edge + shfl reduce.
// ---------------------------------------------------------------------------
__global__ __launch_bounds__(THREADS) void score_kernel(
    const float* __restrict__ z, const int* __restrict__ src,
    const int* __restrict__ dst, float* __restrict__ out, int nedges)
{
    const int gid = blockIdx.x * THREADS + threadIdx.x;
    const int e = gid >> 4;
    const int g = gid & 15;
    if (e >= nedges) return;
    const int s = src[e];
    const int d = dst[e];
    const float4 a = *reinterpret_cast<const float4*>(z + (size_t)s * 64 + g * 4);
    const float4 b = *reinterpret_cast<const float4*>(z + (size_t)d * 64 + g * 4);
    float p = a.x * b.x + a.y * b.y + a.z * b.z + a.w * b.w;
    p += __shfl_down(p, 8, 16);
    p += __shfl_down(p, 4, 16);
    p += __shfl_down(p, 2, 16);
    p += __shfl_down(p, 1, 16);
    if (g == 0) out[e] = p;
}

extern "C" void kernel_launch(void* const* d_in, const int* in_sizes, int n_in,
                              void* d_out, int out_size, void* d_ws, size_t ws_size,
                              hipStream_t stream)
{
    const float* x   = (const float*)d_in[0];   // [N, 128]
    const int*   ei  = (const int*)  d_in[1];   // [2, E]
    const float* W1l = (const float*)d_in[2];   // [128, 64]
    const float* b1  = (const float*)d_in[3];   // [64]
    const float* W1r = (const float*)d_in[4];   // [128, 64]
    const float* W2l = (const float*)d_in[5];   // [64, 64]
    const float* b2  = (const float*)d_in[6];   // [64]
    const float* W2r = (const float*)d_in[7];   // [64, 64]
    float* out = (float*)d_out;

    const int N = in_sizes[0] / 128;            // 50000
    const int E = in_sizes[1] / 2;              // 800000
    const int* src = ei;
    const int* dst = ei + E;

    const size_t N64 = (size_t)N * 64;
    float* tmp    = (float*)d_ws;               // [N,64]  y = in @ Wl
    float* h      = tmp + N64;                  // [N,64]  layer-1 output
    float* z      = h + N64;                    // [N,64]  layer-2 output
    int*   deg    = (int*)(z + N64);            // [N]
    int*   offs   = deg + N;                    // [N]
    int*   cursor = offs + N;                   // [N]
    int*   csr    = cursor + N;                 // [E]
    int*   bsum   = csr + E;                    // [ceil(N/256)]

    constexpr int R = 8;                        // rows per wave
    const int nb          = (N + THREADS - 1) / THREADS;       // scan blocks
    const int edge_blocks = (E + THREADS - 1) / THREADS;
    const int gemm_blocks = (N + 8 * R - 1) / (8 * R);         // exact grid
    const int aggr_blocks = (N + 3) / 4;                       // 4 nodes/block
    const int scor_blocks = (E * 16 + THREADS - 1) / THREADS;

    // ---- CSR build (once; shared by both layers) ----
    hipMemsetAsync(deg, 0, (size_t)N * sizeof(int), stream);
    hist_kernel<<<edge_blocks, THREADS, 0, stream>>>(dst, deg, E);
    scan_reduce<<<nb, THREADS, 0, stream>>>(deg, bsum, N);
    scan_top<<<1, THREADS, 0, stream>>>(bsum, nb);
    scan_apply<<<nb, THREADS, 0, stream>>>(deg, bsum, offs, cursor, N);
    place_kernel<<<edge_blocks, THREADS, 0, stream>>>(src, dst, cursor, csr, E);

    // ---- layer 1 ----
    gemm_dual<128, R><<<gemm_blocks, GTHREADS, 0, stream>>>(x, W1l, W1r, tmp, h, N);
    aggregate_fused<<<aggr_blocks, THREADS, 0, stream>>>(tmp, csr, offs, deg, h, b1, h, N, 1);

    // ---- layer 2 ----
    gemm_dual<64, R><<<gemm_blocks, GTHREADS, 0, stream>>>(h, W2l, W2r, tmp, z, N);
    aggregate_fused<<<aggr_blocks, THREADS, 0, stream>>>(tmp, csr, offs, deg, z, b2, z, N, 0);

    // ---- decode ----
    score_kernel<<<scor_blocks, THREADS, 0, stream>>>(z, src, dst, out, E);
}

// Round 6
// 266.417 us; speedup vs baseline: 1.1819x; 1.1819x over previous
//
#include <hip/hip_runtime.h>
#include <hip/hip_bf16.h>

#define THREADS 256
#define GTHREADS 512   // gemm block size (8 waves)

// ---------------------------------------------------------------------------
// Dual GEMM: outl = in @ Wl, outr = in @ Wr.   in: [nrows, K], W: [K, 64].
// Lane mapping breaks wave-uniformity of x addresses (anti-scalarization):
//   c4 = lane&15  -> output cols [4*c4, 4*c4+4)   (float4 acc)
//   rg = lane>>4  -> row within 4-row group
// Each wave: R iterations x 4 rows = 4R rows, all 64 cols (l and r).
// x loads: per-lane rows => global_load_dwordx4 (vmcnt, in-order, pipelines).
// W staged in LDS by straight coalesced float4 copy; reads are ds_read_b128,
// 16 distinct 16B addrs/wave = 2-way bank aliasing = free.
// Per k4: 128 FMA (256cy) vs 8 ds_read_b128 (~96cy) vs 4 loads -> VALU-bound.
// ---------------------------------------------------------------------------
template<int K, int R>
__global__ __launch_bounds__(GTHREADS, 4) void gemm_dual(
    const float* __restrict__ in, const float* __restrict__ Wl,
    const float* __restrict__ Wr, float* __restrict__ outl,
    float* __restrict__ outr, int nrows)
{
    constexpr int K4 = K / 4;
    __shared__ float4 sWl[K * 16];   // [k][c4] : W[k][4c4..4c4+3]
    __shared__ float4 sWr[K * 16];
    {
        const float4* gWl = reinterpret_cast<const float4*>(Wl);
        const float4* gWr = reinterpret_cast<const float4*>(Wr);
        for (int i = threadIdx.x; i < K * 16; i += GTHREADS) {
            sWl[i] = gWl[i];
            sWr[i] = gWr[i];
        }
    }
    __syncthreads();

    const int lane = threadIdx.x & 63;
    const int wid  = threadIdx.x >> 6;          // 0..7
    const int c4   = lane & 15;                 // col group
    const int rg   = lane >> 4;                 // 0..3 row-in-group
    const int wrow0 = blockIdx.x * (8 * 4 * R) + wid * (4 * R);
    if (wrow0 >= nrows) return;

    int rr[R];
    #pragma unroll
    for (int r = 0; r < R; ++r) {
        const int row = wrow0 + r * 4 + rg;
        rr[r] = (row < nrows) ? row : (nrows - 1);   // clamp loads
    }

    float4 accl[R], accr[R];
    #pragma unroll
    for (int r = 0; r < R; ++r) {
        accl[r] = make_float4(0.f, 0.f, 0.f, 0.f);
        accr[r] = make_float4(0.f, 0.f, 0.f, 0.f);
    }

    #pragma unroll 2
    for (int k4 = 0; k4 < K4; ++k4) {
        float4 xv[R];
        #pragma unroll
        for (int r = 0; r < R; ++r)
            xv[r] = *reinterpret_cast<const float4*>(in + (size_t)rr[r] * K + k4 * 4);

        float4 wl[4], wr[4];
        #pragma unroll
        for (int j = 0; j < 4; ++j) {
            wl[j] = sWl[(k4 * 4 + j) * 16 + c4];
            wr[j] = sWr[(k4 * 4 + j) * 16 + c4];
        }

        #pragma unroll
        for (int r = 0; r < R; ++r) {
            const float x0 = xv[r].x, x1 = xv[r].y, x2 = xv[r].z, x3 = xv[r].w;
            accl[r].x = fmaf(x0, wl[0].x, accl[r].x);
            accl[r].y = fmaf(x0, wl[0].y, accl[r].y);
            accl[r].z = fmaf(x0, wl[0].z, accl[r].z);
            accl[r].w = fmaf(x0, wl[0].w, accl[r].w);
            accl[r].x = fmaf(x1, wl[1].x, accl[r].x);
            accl[r].y = fmaf(x1, wl[1].y, accl[r].y);
            accl[r].z = fmaf(x1, wl[1].z, accl[r].z);
            accl[r].w = fmaf(x1, wl[1].w, accl[r].w);
            accl[r].x = fmaf(x2, wl[2].x, accl[r].x);
            accl[r].y = fmaf(x2, wl[2].y, accl[r].y);
            accl[r].z = fmaf(x2, wl[2].z, accl[r].z);
            accl[r].w = fmaf(x2, wl[2].w, accl[r].w);
            accl[r].x = fmaf(x3, wl[3].x, accl[r].x);
            accl[r].y = fmaf(x3, wl[3].y, accl[r].y);
            accl[r].z = fmaf(x3, wl[3].z, accl[r].z);
            accl[r].w = fmaf(x3, wl[3].w, accl[r].w);

            accr[r].x = fmaf(x0, wr[0].x, accr[r].x);
            accr[r].y = fmaf(x0, wr[0].y, accr[r].y);
            accr[r].z = fmaf(x0, wr[0].z, accr[r].z);
            accr[r].w = fmaf(x0, wr[0].w, accr[r].w);
            accr[r].x = fmaf(x1, wr[1].x, accr[r].x);
            accr[r].y = fmaf(x1, wr[1].y, accr[r].y);
            accr[r].z = fmaf(x1, wr[1].z, accr[r].z);
            accr[r].w = fmaf(x1, wr[1].w, accr[r].w);
            accr[r].x = fmaf(x2, wr[2].x, accr[r].x);
            accr[r].y = fmaf(x2, wr[2].y, accr[r].y);
            accr[r].z = fmaf(x2, wr[2].z, accr[r].z);
            accr[r].w = fmaf(x2, wr[2].w, accr[r].w);
            accr[r].x = fmaf(x3, wr[3].x, accr[r].x);
            accr[r].y = fmaf(x3, wr[3].y, accr[r].y);
            accr[r].z = fmaf(x3, wr[3].z, accr[r].z);
            accr[r].w = fmaf(x3, wr[3].w, accr[r].w);
        }
    }

    #pragma unroll
    for (int r = 0; r < R; ++r) {
        const int row = wrow0 + r * 4 + rg;
        if (row < nrows) {
            *reinterpret_cast<float4*>(outl + (size_t)row * 64 + c4 * 4) = accl[r];
            *reinterpret_cast<float4*>(outr + (size_t)row * 64 + c4 * 4) = accr[r];
        }
    }
}

// ---------------------------------------------------------------------------
// CSR build: histogram of dst, exclusive scan, placement.
// ---------------------------------------------------------------------------
__global__ __launch_bounds__(THREADS) void hist_kernel(
    const int* __restrict__ dst, int* __restrict__ deg, int nedges)
{
    const int e = blockIdx.x * THREADS + threadIdx.x;
    if (e < nedges) atomicAdd(&deg[dst[e]], 1);
}

__global__ __launch_bounds__(THREADS) void scan_reduce(
    const int* __restrict__ deg, int* __restrict__ bsum, int n)
{
    __shared__ int s[THREADS];
    const int i = blockIdx.x * THREADS + threadIdx.x;
    s[threadIdx.x] = (i < n) ? deg[i] : 0;
    __syncthreads();
    for (int off = THREADS / 2; off > 0; off >>= 1) {
        if (threadIdx.x < off) s[threadIdx.x] += s[threadIdx.x + off];
        __syncthreads();
    }
    if (threadIdx.x == 0) bsum[blockIdx.x] = s[0];
}

// single block; nb <= THREADS
__global__ __launch_bounds__(THREADS) void scan_top(int* __restrict__ bsum, int nb)
{
    __shared__ int s[THREADS];
    const int t = threadIdx.x;
    const int v = (t < nb) ? bsum[t] : 0;
    s[t] = v;
    __syncthreads();
    for (int off = 1; off < THREADS; off <<= 1) {
        const int a = (t >= off) ? s[t - off] : 0;
        __syncthreads();
        s[t] += a;
        __syncthreads();
    }
    if (t < nb) bsum[t] = s[t] - v;   // exclusive
}

__global__ __launch_bounds__(THREADS) void scan_apply(
    const int* __restrict__ deg, const int* __restrict__ bsum,
    int* __restrict__ offs, int* __restrict__ cursor, int n)
{
    __shared__ int s[THREADS];
    const int t = threadIdx.x;
    const int i = blockIdx.x * THREADS + t;
    const int v = (i < n) ? deg[i] : 0;
    s[t] = v;
    __syncthreads();
    for (int off = 1; off < THREADS; off <<= 1) {
        const int a = (t >= off) ? s[t - off] : 0;
        __syncthreads();
        s[t] += a;
        __syncthreads();
    }
    if (i < n) {
        const int ex = bsum[blockIdx.x] + s[t] - v;
        offs[i] = ex;
        cursor[i] = ex;
    }
}

__global__ __launch_bounds__(THREADS) void place_kernel(
    const int* __restrict__ src, const int* __restrict__ dst,
    int* __restrict__ cursor, int* __restrict__ csr, int nedges)
{
    const int e = blockIdx.x * THREADS + threadIdx.x;
    if (e < nedges) {
        const int pos = atomicAdd(&cursor[dst[e]], 1);
        csr[pos] = src[e];
    }
}

// ---------------------------------------------------------------------------
// Fused mean-aggregate + combine:
//   out[node,lane] = [relu]( (sum_{s in csr[node]} y[s,lane]) / max(deg,1)
//                            + bias[lane] + right[node,lane] )
// One wave per node, lane = channel. Edge rows are coalesced 256B gathers.
// ---------------------------------------------------------------------------
__global__ __launch_bounds__(THREADS) void aggregate_fused(
    const float* __restrict__ y, const int* __restrict__ csr,
    const int* __restrict__ offs, const int* __restrict__ deg,
    const float* __restrict__ right, const float* __restrict__ bias,
    float* __restrict__ out, int n, int relu)
{
    int node = blockIdx.x * (THREADS / 64) + (threadIdx.x >> 6);
    if (node >= n) return;
    node = __builtin_amdgcn_readfirstlane(node);   // wave-uniform
    const int lane = threadIdx.x & 63;
    const int start = __builtin_amdgcn_readfirstlane(offs[node]);
    const int d     = __builtin_amdgcn_readfirstlane(deg[node]);

    float acc = 0.f;
    int i = 0;
    for (; i + 4 <= d; i += 4) {
        const int s0 = __builtin_amdgcn_readfirstlane(csr[start + i + 0]);
        const int s1 = __builtin_amdgcn_readfirstlane(csr[start + i + 1]);
        const int s2 = __builtin_amdgcn_readfirstlane(csr[start + i + 2]);
        const int s3 = __builtin_amdgcn_readfirstlane(csr[start + i + 3]);
        const float a0 = y[(size_t)s0 * 64 + lane];
        const float a1 = y[(size_t)s1 * 64 + lane];
        const float a2 = y[(size_t)s2 * 64 + lane];
        const float a3 = y[(size_t)s3 * 64 + lane];
        acc += a0 + a1 + a2 + a3;
    }
    for (; i < d; ++i) {
        const int s = __builtin_amdgcn_readfirstlane(csr[start + i]);
        acc += y[(size_t)s * 64 + lane];
    }

    const float inv = 1.0f / (float)(d > 0 ? d : 1);
    float v = fmaf(acc, inv, bias[lane] + right[(size_t)node * 64 + lane]);
    if (relu) v = fmaxf(v, 0.f);
    out[(size_t)node * 64 + lane] = v;
}

// ---------------------------------------------------------------------------
// out[e] = dot(z[src[e]], z[dst[e]])  over 64 ch; 16 lanes/edge + shfl reduce.
// ---------------------------------------------------------------------------
__global__ __launch_bounds__(THREADS) void score_kernel(
    const float* __restrict__ z, const int* __restrict__ src,
    const int* __restrict__ dst, float* __restrict__ out, int nedges)
{
    const int gid = blockIdx.x * THREADS + threadIdx.x;
    const int e = gid >> 4;
    const int g = gid & 15;
    if (e >= nedges) return;
    const int s = src[e];
    const int d = dst[e];
    const float4 a = *reinterpret_cast<const float4*>(z + (size_t)s * 64 + g * 4);
    const float4 b = *reinterpret_cast<const float4*>(z + (size_t)d * 64 + g * 4);
    float p = a.x * b.x + a.y * b.y + a.z * b.z + a.w * b.w;
    p += __shfl_down(p, 8, 16);
    p += __shfl_down(p, 4, 16);
    p += __shfl_down(p, 2, 16);
    p += __shfl_down(p, 1, 16);
    if (g == 0) out[e] = p;
}

extern "C" void kernel_launch(void* const* d_in, const int* in_sizes, int n_in,
                              void* d_out, int out_size, void* d_ws, size_t ws_size,
                              hipStream_t stream)
{
    const float* x   = (const float*)d_in[0];   // [N, 128]
    const int*   ei  = (const int*)  d_in[1];   // [2, E]
    const float* W1l = (const float*)d_in[2];   // [128, 64]
    const float* b1  = (const float*)d_in[3];   // [64]
    const float* W1r = (const float*)d_in[4];   // [128, 64]
    const float* W2l = (const float*)d_in[5];   // [64, 64]
    const float* b2  = (const float*)d_in[6];   // [64]
    const float* W2r = (const float*)d_in[7];   // [64, 64]
    float* out = (float*)d_out;

    const int N = in_sizes[0] / 128;            // 50000
    const int E = in_sizes[1] / 2;              // 800000
    const int* src = ei;
    const int* dst = ei + E;

    const size_t N64 = (size_t)N * 64;
    float* tmp    = (float*)d_ws;               // [N,64]  y = in @ Wl
    float* h      = tmp + N64;                  // [N,64]  layer-1 output
    float* z      = h + N64;                    // [N,64]  layer-2 output
    int*   deg    = (int*)(z + N64);            // [N]
    int*   offs   = deg + N;                    // [N]
    int*   cursor = offs + N;                   // [N]
    int*   csr    = cursor + N;                 // [E]
    int*   bsum   = csr + E;                    // [ceil(N/256)]

    constexpr int R = 4;                        // row-iters per lane
    const int rows_per_block = 8 * 4 * R;       // 8 waves x 4 rows x R
    const int nb          = (N + THREADS - 1) / THREADS;       // scan blocks
    const int edge_blocks = (E + THREADS - 1) / THREADS;
    const int gemm_blocks = (N + rows_per_block - 1) / rows_per_block;
    const int aggr_blocks = (N + 3) / 4;                       // 4 nodes/block
    const int scor_blocks = (E * 16 + THREADS - 1) / THREADS;

    // ---- CSR build (once; shared by both layers) ----
    hipMemsetAsync(deg, 0, (size_t)N * sizeof(int), stream);
    hist_kernel<<<edge_blocks, THREADS, 0, stream>>>(dst, deg, E);
    scan_reduce<<<nb, THREADS, 0, stream>>>(deg, bsum, N);
    scan_top<<<1, THREADS, 0, stream>>>(bsum, nb);
    scan_apply<<<nb, THREADS, 0, stream>>>(deg, bsum, offs, cursor, N);
    place_kernel<<<edge_blocks, THREADS, 0, stream>>>(src, dst, cursor, csr, E);

    // ---- layer 1 ----
    gemm_dual<128, R><<<gemm_blocks, GTHREADS, 0, stream>>>(x, W1l, W1r, tmp, h, N);
    aggregate_fused<<<aggr_blocks, THREADS, 0, stream>>>(tmp, csr, offs, deg, h, b1, h, N, 1);

    // ---- layer 2 ----
    gemm_dual<64, R><<<gemm_blocks, GTHREADS, 0, stream>>>(h, W2l, W2r, tmp, z, N);
    aggregate_fused<<<aggr_blocks, THREADS, 0, stream>>>(tmp, csr, offs, deg, z, b2, z, N, 0);

    // ---- decode ----
    score_kernel<<<scor_blocks, THREADS, 0, stream>>>(z, src, dst, out, E);
}

// Round 7
// 222.825 us; speedup vs baseline: 1.4131x; 1.1956x over previous
//
#include <hip/hip_runtime.h>
#include <hip/hip_bf16.h>

#define THREADS 256
#define GTHREADS 512   // gemm block size (8 waves)

typedef _Float16 half4_t __attribute__((ext_vector_type(4)));
typedef _Float16 half8_t __attribute__((ext_vector_type(8)));

__device__ inline float4 load4(const float* p) {
    return *reinterpret_cast<const float4*>(p);
}
__device__ inline float4 load4(const _Float16* p) {
    const half4_t t = *reinterpret_cast<const half4_t*>(p);
    return make_float4((float)t.x, (float)t.y, (float)t.z, (float)t.w);
}
__device__ inline void store4h(_Float16* p, float4 v) {
    half4_t t;
    t.x = (_Float16)v.x; t.y = (_Float16)v.y;
    t.z = (_Float16)v.z; t.w = (_Float16)v.w;
    *reinterpret_cast<half4_t*>(p) = t;
}

// ---------------------------------------------------------------------------
// Dual GEMM: outl = in @ Wl, outr = in @ Wr.   in: [nrows, K] (fp32 or fp16),
// W: [K, 64] fp32, outputs fp16. Lane mapping breaks wave-uniformity of x
// addresses (anti-scalarization): c4 = lane&15 -> cols, rg = lane>>4 -> row.
// x loads: per-lane rows => global vector loads (vmcnt path, pipelines).
// W staged in LDS via straight coalesced float4 copy; ds_read_b128, 2-way
// bank aliasing = free. Per k4: 128 FMA vs 8 ds_read_b128 -> VALU-bound.
// ---------------------------------------------------------------------------
template<typename Tin, int K, int R>
__global__ __launch_bounds__(GTHREADS, 4) void gemm_dual(
    const Tin* __restrict__ in, const float* __restrict__ Wl,
    const float* __restrict__ Wr, _Float16* __restrict__ outl,
    _Float16* __restrict__ outr, int nrows)
{
    constexpr int K4 = K / 4;
    __shared__ float4 sWl[K * 16];   // [k][c4] : W[k][4c4..4c4+3]
    __shared__ float4 sWr[K * 16];
    {
        const float4* gWl = reinterpret_cast<const float4*>(Wl);
        const float4* gWr = reinterpret_cast<const float4*>(Wr);
        for (int i = threadIdx.x; i < K * 16; i += GTHREADS) {
            sWl[i] = gWl[i];
            sWr[i] = gWr[i];
        }
    }
    __syncthreads();

    const int lane = threadIdx.x & 63;
    const int wid  = threadIdx.x >> 6;          // 0..7
    const int c4   = lane & 15;                 // col group
    const int rg   = lane >> 4;                 // 0..3 row-in-group
    const int wrow0 = blockIdx.x * (8 * 4 * R) + wid * (4 * R);
    if (wrow0 >= nrows) return;

    int rr[R];
    #pragma unroll
    for (int r = 0; r < R; ++r) {
        const int row = wrow0 + r * 4 + rg;
        rr[r] = (row < nrows) ? row : (nrows - 1);   // clamp loads
    }

    float4 accl[R], accr[R];
    #pragma unroll
    for (int r = 0; r < R; ++r) {
        accl[r] = make_float4(0.f, 0.f, 0.f, 0.f);
        accr[r] = make_float4(0.f, 0.f, 0.f, 0.f);
    }

    #pragma unroll 2
    for (int k4 = 0; k4 < K4; ++k4) {
        float4 xv[R];
        #pragma unroll
        for (int r = 0; r < R; ++r)
            xv[r] = load4(in + (size_t)rr[r] * K + k4 * 4);

        float4 wl[4], wr[4];
        #pragma unroll
        for (int j = 0; j < 4; ++j) {
            wl[j] = sWl[(k4 * 4 + j) * 16 + c4];
            wr[j] = sWr[(k4 * 4 + j) * 16 + c4];
        }

        #pragma unroll
        for (int r = 0; r < R; ++r) {
            const float x0 = xv[r].x, x1 = xv[r].y, x2 = xv[r].z, x3 = xv[r].w;
            accl[r].x = fmaf(x0, wl[0].x, accl[r].x);
            accl[r].y = fmaf(x0, wl[0].y, accl[r].y);
            accl[r].z = fmaf(x0, wl[0].z, accl[r].z);
            accl[r].w = fmaf(x0, wl[0].w, accl[r].w);
            accl[r].x = fmaf(x1, wl[1].x, accl[r].x);
            accl[r].y = fmaf(x1, wl[1].y, accl[r].y);
            accl[r].z = fmaf(x1, wl[1].z, accl[r].z);
            accl[r].w = fmaf(x1, wl[1].w, accl[r].w);
            accl[r].x = fmaf(x2, wl[2].x, accl[r].x);
            accl[r].y = fmaf(x2, wl[2].y, accl[r].y);
            accl[r].z = fmaf(x2, wl[2].z, accl[r].z);
            accl[r].w = fmaf(x2, wl[2].w, accl[r].w);
            accl[r].x = fmaf(x3, wl[3].x, accl[r].x);
            accl[r].y = fmaf(x3, wl[3].y, accl[r].y);
            accl[r].z = fmaf(x3, wl[3].z, accl[r].z);
            accl[r].w = fmaf(x3, wl[3].w, accl[r].w);

            accr[r].x = fmaf(x0, wr[0].x, accr[r].x);
            accr[r].y = fmaf(x0, wr[0].y, accr[r].y);
            accr[r].z = fmaf(x0, wr[0].z, accr[r].z);
            accr[r].w = fmaf(x0, wr[0].w, accr[r].w);
            accr[r].x = fmaf(x1, wr[1].x, accr[r].x);
            accr[r].y = fmaf(x1, wr[1].y, accr[r].y);
            accr[r].z = fmaf(x1, wr[1].z, accr[r].z);
            accr[r].w = fmaf(x1, wr[1].w, accr[r].w);
            accr[r].x = fmaf(x2, wr[2].x, accr[r].x);
            accr[r].y = fmaf(x2, wr[2].y, accr[r].y);
            accr[r].z = fmaf(x2, wr[2].z, accr[r].z);
            accr[r].w = fmaf(x2, wr[2].w, accr[r].w);
            accr[r].x = fmaf(x3, wr[3].x, accr[r].x);
            accr[r].y = fmaf(x3, wr[3].y, accr[r].y);
            accr[r].z = fmaf(x3, wr[3].z, accr[r].z);
            accr[r].w = fmaf(x3, wr[3].w, accr[r].w);
        }
    }

    #pragma unroll
    for (int r = 0; r < R; ++r) {
        const int row = wrow0 + r * 4 + rg;
        if (row < nrows) {
            store4h(outl + (size_t)row * 64 + c4 * 4, accl[r]);
            store4h(outr + (size_t)row * 64 + c4 * 4, accr[r]);
        }
    }
}

// ---------------------------------------------------------------------------
// CSR build: histogram of dst, exclusive scan, placement.
// ---------------------------------------------------------------------------
__global__ __launch_bounds__(THREADS) void hist_kernel(
    const int* __restrict__ dst, int* __restrict__ deg, int nedges)
{
    const int e = blockIdx.x * THREADS + threadIdx.x;
    if (e < nedges) atomicAdd(&deg[dst[e]], 1);
}

__global__ __launch_bounds__(THREADS) void scan_reduce(
    const int* __restrict__ deg, int* __restrict__ bsum, int n)
{
    __shared__ int s[THREADS];
    const int i = blockIdx.x * THREADS + threadIdx.x;
    s[threadIdx.x] = (i < n) ? deg[i] : 0;
    __syncthreads();
    for (int off = THREADS / 2; off > 0; off >>= 1) {
        if (threadIdx.x < off) s[threadIdx.x] += s[threadIdx.x + off];
        __syncthreads();
    }
    if (threadIdx.x == 0) bsum[blockIdx.x] = s[0];
}

// single block; nb <= THREADS
__global__ __launch_bounds__(THREADS) void scan_top(int* __restrict__ bsum, int nb)
{
    __shared__ int s[THREADS];
    const int t = threadIdx.x;
    const int v = (t < nb) ? bsum[t] : 0;
    s[t] = v;
    __syncthreads();
    for (int off = 1; off < THREADS; off <<= 1) {
        const int a = (t >= off) ? s[t - off] : 0;
        __syncthreads();
        s[t] += a;
        __syncthreads();
    }
    if (t < nb) bsum[t] = s[t] - v;   // exclusive
}

__global__ __launch_bounds__(THREADS) void scan_apply(
    const int* __restrict__ deg, const int* __restrict__ bsum,
    int* __restrict__ offs, int* __restrict__ cursor, int n)
{
    __shared__ int s[THREADS];
    const int t = threadIdx.x;
    const int i = blockIdx.x * THREADS + t;
    const int v = (i < n) ? deg[i] : 0;
    s[t] = v;
    __syncthreads();
    for (int off = 1; off < THREADS; off <<= 1) {
        const int a = (t >= off) ? s[t - off] : 0;
        __syncthreads();
        s[t] += a;
        __syncthreads();
    }
    if (i < n) {
        const int ex = bsum[blockIdx.x] + s[t] - v;
        offs[i] = ex;
        cursor[i] = ex;
    }
}

__global__ __launch_bounds__(THREADS) void place_kernel(
    const int* __restrict__ src, const int* __restrict__ dst,
    int* __restrict__ cursor, int* __restrict__ csr, int nedges)
{
    const int e = blockIdx.x * THREADS + threadIdx.x;
    if (e < nedges) {
        const int pos = atomicAdd(&cursor[dst[e]], 1);
        csr[pos] = src[e];
    }
}

// ---------------------------------------------------------------------------
// Fused mean-aggregate + combine (fp16 payload, fp32 accumulation):
//   out[node,lane] = [relu]( (sum_{s in csr[node]} y[s,lane]) / max(deg,1)
//                            + bias[lane] + right[node,lane] )
// One wave per node, lane = channel. Each row read = one coalesced 128B
// wave transaction (64 lanes x 2B).
// ---------------------------------------------------------------------------
__global__ __launch_bounds__(THREADS) void aggregate_fused(
    const _Float16* __restrict__ y, const int* __restrict__ csr,
    const int* __restrict__ offs, const int* __restrict__ deg,
    const _Float16* __restrict__ right, const float* __restrict__ bias,
    _Float16* __restrict__ out, int n, int relu)
{
    int node = blockIdx.x * (THREADS / 64) + (threadIdx.x >> 6);
    if (node >= n) return;
    node = __builtin_amdgcn_readfirstlane(node);   // wave-uniform
    const int lane = threadIdx.x & 63;
    const int start = __builtin_amdgcn_readfirstlane(offs[node]);
    const int d     = __builtin_amdgcn_readfirstlane(deg[node]);

    float acc = 0.f;
    int i = 0;
    for (; i + 4 <= d; i += 4) {
        const int s0 = __builtin_amdgcn_readfirstlane(csr[start + i + 0]);
        const int s1 = __builtin_amdgcn_readfirstlane(csr[start + i + 1]);
        const int s2 = __builtin_amdgcn_readfirstlane(csr[start + i + 2]);
        const int s3 = __builtin_amdgcn_readfirstlane(csr[start + i + 3]);
        const float a0 = (float)y[(size_t)s0 * 64 + lane];
        const float a1 = (float)y[(size_t)s1 * 64 + lane];
        const float a2 = (float)y[(size_t)s2 * 64 + lane];
        const float a3 = (float)y[(size_t)s3 * 64 + lane];
        acc += a0 + a1 + a2 + a3;
    }
    for (; i < d; ++i) {
        const int s = __builtin_amdgcn_readfirstlane(csr[start + i]);
        acc += (float)y[(size_t)s * 64 + lane];
    }

    const float inv = 1.0f / (float)(d > 0 ? d : 1);
    float v = fmaf(acc, inv, bias[lane] + (float)right[(size_t)node * 64 + lane]);
    if (relu) v = fmaxf(v, 0.f);
    out[(size_t)node * 64 + lane] = (_Float16)v;
}

// ---------------------------------------------------------------------------
// out[e] = dot(z[src[e]], z[dst[e]]) over 64 ch (fp16 z, fp32 accum);
// 8 lanes/edge, 16B loads, shfl reduce over 8.
// ---------------------------------------------------------------------------
__global__ __launch_bounds__(THREADS) void score_kernel(
    const _Float16* __restrict__ z, const int* __restrict__ src,
    const int* __restrict__ dst, float* __restrict__ out, int nedges)
{
    const int gid = blockIdx.x * THREADS + threadIdx.x;
    const int e = gid >> 3;
    const int g = gid & 7;
    if (e >= nedges) return;
    const int s = src[e];
    const int d = dst[e];
    const half8_t a = *reinterpret_cast<const half8_t*>(z + (size_t)s * 64 + g * 8);
    const half8_t b = *reinterpret_cast<const half8_t*>(z + (size_t)d * 64 + g * 8);
    float p = 0.f;
    #pragma unroll
    for (int j = 0; j < 8; ++j)
        p = fmaf((float)a[j], (float)b[j], p);
    p += __shfl_down(p, 4, 8);
    p += __shfl_down(p, 2, 8);
    p += __shfl_down(p, 1, 8);
    if (g == 0) out[e] = p;
}

extern "C" void kernel_launch(void* const* d_in, const int* in_sizes, int n_in,
                              void* d_out, int out_size, void* d_ws, size_t ws_size,
                              hipStream_t stream)
{
    const float* x   = (const float*)d_in[0];   // [N, 128]
    const int*   ei  = (const int*)  d_in[1];   // [2, E]
    const float* W1l = (const float*)d_in[2];   // [128, 64]
    const float* b1  = (const float*)d_in[3];   // [64]
    const float* W1r = (const float*)d_in[4];   // [128, 64]
    const float* W2l = (const float*)d_in[5];   // [64, 64]
    const float* b2  = (const float*)d_in[6];   // [64]
    const float* W2r = (const float*)d_in[7];   // [64, 64]
    float* out = (float*)d_out;

    const int N = in_sizes[0] / 128;            // 50000
    const int E = in_sizes[1] / 2;              // 800000
    const int* src = ei;
    const int* dst = ei + E;

    const size_t N64 = (size_t)N * 64;
    _Float16* tmp = (_Float16*)d_ws;            // [N,64]  in @ Wl (messages)
    _Float16* h   = tmp + N64;                  // [N,64]  layer-1 output
    _Float16* z   = h + N64;                    // [N,64]  layer-2 output
    int* deg    = (int*)(z + N64);              // [N]
    int* offs   = deg + N;                      // [N]
    int* cursor = offs + N;                     // [N]
    int* csr    = cursor + N;                   // [E]
    int* bsum   = csr + E;                      // [ceil(N/256)]

    constexpr int R = 4;                        // row-iters per lane
    const int rows_per_block = 8 * 4 * R;       // 8 waves x 4 rows x R
    const int nb          = (N + THREADS - 1) / THREADS;       // scan blocks
    const int edge_blocks = (E + THREADS - 1) / THREADS;
    const int gemm_blocks = (N + rows_per_block - 1) / rows_per_block;
    const int aggr_blocks = (N + 3) / 4;                       // 4 nodes/block
    const int scor_blocks = (E * 8 + THREADS - 1) / THREADS;

    // ---- CSR build (once; shared by both layers) ----
    hipMemsetAsync(deg, 0, (size_t)N * sizeof(int), stream);
    hist_kernel<<<edge_blocks, THREADS, 0, stream>>>(dst, deg, E);
    scan_reduce<<<nb, THREADS, 0, stream>>>(deg, bsum, N);
    scan_top<<<1, THREADS, 0, stream>>>(bsum, nb);
    scan_apply<<<nb, THREADS, 0, stream>>>(deg, bsum, offs, cursor, N);
    place_kernel<<<edge_blocks, THREADS, 0, stream>>>(src, dst, cursor, csr, E);

    // ---- layer 1 ----
    gemm_dual<float, 128, R><<<gemm_blocks, GTHREADS, 0, stream>>>(x, W1l, W1r, tmp, h, N);
    aggregate_fused<<<aggr_blocks, THREADS, 0, stream>>>(tmp, csr, offs, deg, h, b1, h, N, 1);

    // ---- layer 2 ----
    gemm_dual<_Float16, 64, R><<<gemm_blocks, GTHREADS, 0, stream>>>(h, W2l, W2r, tmp, z, N);
    aggregate_fused<<<aggr_blocks, THREADS, 0, stream>>>(tmp, csr, offs, deg, z, b2, z, N, 0);

    // ---- decode ----
    score_kernel<<<scor_blocks, THREADS, 0, stream>>>(z, src, dst, out, E);
}